// Round 13
// baseline (883.365 us; speedup 1.0000x reference)
//
#include <hip/hip_runtime.h>
#include <hip/hip_bf16.h>
#include <stdint.h>

// GCNDecoder: persistent blocks, COLUMN-SPLIT (r11 body, numerically verified) with the
// measured-safe allocator attribute: amdgpu_waves_per_eu(2,4).
//   - budget model (r9-r12 measured): regs_cap = 256/min_waves => min=2 -> 128 (no spill),
//     min=4 -> 64 (always spills). So min MUST be 2.
//   - max=4 (not 2) so hardware residency is not clamped: ~100 total regs/wave
//     (bf8[8]=32 + acc[4]=16 + pf=16 + misc) and 66KB LDS allow 2 blocks/CU.
// 512 blocks x 512 thr (8 waves x 16 cols = 128 of 256 output cols per block).
// XCD pairing: blocks b,b^8 share an XCD (dispatch %8) and the same tile range ->
// partner's A-tile reads hit L2. Schedule (store-free where possible):
//  K1: gather->G4 -> buf=Y4raw, stats4      K2: Y4raw --act4--> G1 -> stats1 (no store)
//  K3: Y4raw --act4-->h; out1=act1+h -> buf; out[e] += out1.wf (atomic, seeded bf)
//  K4: out1 -> G2 -> stats2 (no store)      K5: out1 -> G2 -> out[e] += act2.wf
// Stats: reg accum -> LDS reduce -> xcd-sliced fp32 atomics once per block.

typedef __attribute__((ext_vector_type(8))) short short8;
typedef __attribute__((ext_vector_type(4))) float f32x4;

__device__ __forceinline__ unsigned short bf16b(float f) {
  unsigned int u = __float_as_uint(f);
  return (unsigned short)((u + 0x7fffu + ((u >> 16) & 1u)) >> 16);  // RNE
}
__device__ __forceinline__ unsigned int packbf(float lo, float hi) {
  return (unsigned int)bf16b(lo) | ((unsigned int)bf16b(hi) << 16);
}
__device__ __forceinline__ float bflo(unsigned int u) { return __uint_as_float(u << 16); }
__device__ __forceinline__ float bfhi(unsigned int u) { return __uint_as_float(u & 0xffff0000u); }
__device__ __forceinline__ float bfs(short s) { return __uint_as_float(((unsigned int)(unsigned short)s) << 16); }
__device__ __forceinline__ float relu_(float x) { return fmaxf(x, 0.0f); }

// ---- tiny kernels ----
__global__ __launch_bounds__(256) void k_init(const int* __restrict__ ei,
                                              float* __restrict__ stats, int* __restrict__ flag) {
  const int t = threadIdx.x;
  for (int i = t; i < 12288; i += 256) stats[i] = 0.f;
  if (t == 0) {
    int o = 0;
#pragma unroll
    for (int i = 0; i < 32; ++i) o |= ei[2 * i + 1];
    *flag = (o == 0) ? 1 : 0;  // 1 => int64 pairs, 0 => int32
  }
}

__global__ __launch_bounds__(256) void k_seed(float* __restrict__ out, const float* __restrict__ bfp, int E) {
  const int i = blockIdx.x * 256 + threadIdx.x;
  if (i < E) out[i] = bfp[0];
}

// Wt[n][k] = bf16(W[k][n])  (n-major, 512B rows)
__global__ __launch_bounds__(256) void k_prep(
    const float* __restrict__ W4, const float* __restrict__ W1, const float* __restrict__ W2,
    unsigned short* __restrict__ wt4, unsigned short* __restrict__ wt1, unsigned short* __restrict__ wt2)
{
  const int b = blockIdx.x;
  const int t = threadIdx.x;
  const int wi = b >> 6;
  const int r = b & 63;
  const float* W = (wi == 0) ? W4 : (wi == 1) ? W1 : W2;
  unsigned short* Wt = (wi == 0) ? wt4 : (wi == 1) ? wt1 : wt2;
  const int flat = r * 1024 + t * 4;
  const int n = flat >> 8;
  const int k = flat & 255;
  ushort4 o;
  o.x = bf16b(W[(k + 0) * 256 + n]);
  o.y = bf16b(W[(k + 1) * 256 + n]);
  o.z = bf16b(W[(k + 2) * 256 + n]);
  o.w = bf16b(W[(k + 3) * 256 + n]);
  *(ushort4*)(Wt + flat) = o;
}

// stats (8 slices) -> scale[c]=a, scale[256+c]=c_std, scale[512+c]=c_b (bias folded)
__global__ __launch_bounds__(256) void k_stats(
    const float* __restrict__ stats, const float* __restrict__ g, const float* __restrict__ be,
    const float* __restrict__ bias, float* __restrict__ scale, float invE)
{
  const int c = threadIdx.x;
  float s = 0.f, q = 0.f;
#pragma unroll
  for (int sl = 0; sl < 8; ++sl) { s += stats[sl * 512 + c]; q += stats[sl * 512 + 256 + c]; }
  const float mean = s * invE;
  const float var = q * invE - mean * mean;
  const float a = g[c] * rsqrtf(var + 1e-5f);
  const float cstd = be[c] - mean * a;
  scale[c] = a;
  scale[256 + c] = cstd;
  scale[512 + c] = fmaf(a, bias[c], cstd);
}

__global__ __launch_bounds__(256) void k_bail(float* __restrict__ out, const float* __restrict__ bfp, int E) {
  const int i = blockIdx.x * 256 + threadIdx.x;
  if (i < E) out[i] = bfp[0];
}

// ---- persistent GEMM pass, column-split (8 waves x 16 cols = 128 cols per block) ----
// MODE 1: A=gather(x); store raw half; stats      MODE 2: A=act(buf); stats only
// MODE 3: A=act(buf)=h; out1=act1(acc)+h; store half; out[e] += out1.wf (atomic)
// MODE 4: A=buf raw; stats only                   MODE 5: A=buf raw; out[e]+=act2.wf
template<int MODE>
__global__ __attribute__((amdgpu_waves_per_eu(2, 4))) __launch_bounds__(512) void kp(
    const void* Asrc, const int* __restrict__ ei, const int* __restrict__ flagp,
    const unsigned short* __restrict__ Wt, const float* __restrict__ bias,
    const float* __restrict__ scst, const float* __restrict__ scep, const float* __restrict__ wf,
    unsigned short* __restrict__ buf, float* __restrict__ stats, float* __restrict__ out,
    int E, int MT)
{
  __shared__ __align__(16) char lds[65536];  // A tile double-buffer (2 x 32KB)
  __shared__ float sRed[512];                // dot-reduce (64x8) / stats-reduce (256)

  const int t = threadIdx.x;
  const int b = blockIdx.x;
  // XCD pairing: b and b^8 share an XCD; same tile range, opposite col halves.
  const int xcd = b & 7;
  const int slot = b >> 3;                   // 0..63
  const int half = slot & 1;
  const int g = xcd * 32 + (slot >> 1);      // 0..255 tile-range group
  const int per = MT >> 8, rem = MT & 255;
  const int t0 = g * per + (g < rem ? g : rem);
  const int t1 = t0 + per + (g < rem ? 1 : 0);

  const int l = t & 63, wv = t >> 6;         // 8 waves x 16 cols
  const int sw = (l & 7) << 4;
  const int subc = t & 31;                   // invariant across c = t + r*512
  const int lrq = (l >> 4) << 2;
  const int kq = (l >> 4) << 4;              // byte k-offset within 64B slice
  const int colfull = half * 128 + wv * 16 + (l & 15);
  const int flag = (MODE == 1) ? flagp[0] : 0;

  float bj = 0.f;
  if (MODE == 1 || MODE == 2 || MODE == 4) bj = bias[colfull];
  float aE = 0.f, cE = 0.f, wE = 0.f;
  if (MODE == 3 || MODE == 5) { aE = scep[colfull]; cE = scep[512 + colfull]; wE = wf[colfull]; }
  float4 aa0, aa1, cc0, cc1;                 // staging act scales (loop-invariant per thread)
  if (MODE == 2 || MODE == 3) {
    aa0 = *(const float4*)(scst + subc * 8);
    aa1 = *(const float4*)(scst + subc * 8 + 4);
    cc0 = *(const float4*)(scst + 512 + subc * 8);
    cc1 = *(const float4*)(scst + 512 + subc * 8 + 4);
  }
  float ssum = 0.f, ssq = 0.f;

  uint4 pf[4];
#define PREFETCH(TT)                                                            \
  if (MODE == 1) {                                                              \
    const float* xf = (const float*)Asrc;                                       \
    _Pragma("unroll")                                                           \
    for (int r = 0; r < 4; ++r) {                                               \
      const int c = t + r * 512;                                                \
      const int row = c >> 5;                                                   \
      int e = (TT) * 64 + row; if (e >= E) e = E - 1;                           \
      const int idx = (subc < 16) ? e : (E + e);                                \
      const int node = flag ? ei[2 * idx] : ei[idx];                            \
      const float* s = xf + node * 128 + (subc & 15) * 8;                       \
      float4 f0 = *(const float4*)s;                                            \
      float4 f1 = *(const float4*)(s + 4);                                      \
      pf[r].x = packbf(f0.x, f0.y); pf[r].y = packbf(f0.z, f0.w);               \
      pf[r].z = packbf(f1.x, f1.y); pf[r].w = packbf(f1.z, f1.w);               \
    }                                                                           \
  } else {                                                                      \
    const uint4* s = (const uint4*)((const char*)Asrc + (size_t)(TT) * 32768);  \
    _Pragma("unroll")                                                           \
    for (int r = 0; r < 4; ++r) pf[r] = s[t + r * 512];                         \
  }

#define STAGE_A(AP)                                                             \
  _Pragma("unroll")                                                             \
  for (int r = 0; r < 4; ++r) {                                                 \
    const int c = t + r * 512;                                                  \
    const int row = c >> 5;                                                     \
    uint4 v = pf[r];                                                            \
    if (MODE == 2 || MODE == 3) {                                               \
      unsigned int* vp = (unsigned int*)&v;                                     \
      vp[0] = packbf(relu_(fmaf(bflo(vp[0]), aa0.x, cc0.x)),                    \
                     relu_(fmaf(bfhi(vp[0]), aa0.y, cc0.y)));                   \
      vp[1] = packbf(relu_(fmaf(bflo(vp[1]), aa0.z, cc0.z)),                    \
                     relu_(fmaf(bfhi(vp[1]), aa0.w, cc0.w)));                   \
      vp[2] = packbf(relu_(fmaf(bflo(vp[2]), aa1.x, cc1.x)),                    \
                     relu_(fmaf(bfhi(vp[2]), aa1.y, cc1.y)));                   \
      vp[3] = packbf(relu_(fmaf(bflo(vp[3]), aa1.z, cc1.z)),                    \
                     relu_(fmaf(bfhi(vp[3]), aa1.w, cc1.w)));                   \
    }                                                                           \
    *(uint4*)((AP) + row * 512 + ((subc * 16) ^ ((row & 7) << 4))) = v;         \
  }

  PREFETCH(t0);
  // ---- B fragments: direct global -> registers (32 VGPR; one-time, L2-resident) ----
  short8 bf8[8];
  {
    const unsigned short* wp = Wt + (unsigned)colfull * 256 + ((l >> 4) << 3);
#pragma unroll
    for (int s8 = 0; s8 < 8; ++s8)
      bf8[s8] = *(const short8*)(wp + s8 * 32);
  }

  char* aT0 = lds;
  char* aT1 = lds + 32768;

  STAGE_A(aT0);
  if (t0 + 1 < t1) PREFETCH(t0 + 1);
  __syncthreads();

  int cur = 0;
  for (int tt = t0; tt < t1; ++tt) {
    char* aC = cur ? aT1 : aT0;
    char* aN = cur ? aT0 : aT1;
    if (tt + 1 < t1) {
      STAGE_A(aN);                           // overlaps with MFMA (no barrier between)
      if (tt + 2 < t1) PREFETCH(tt + 2);
    }

    f32x4 acc[4];
    f32x4 zz = {0.f, 0.f, 0.f, 0.f};
    acc[0] = zz; acc[1] = zz; acc[2] = zz; acc[3] = zz;
#pragma unroll
    for (int s8 = 0; s8 < 8; ++s8) {
      const int kb = (s8 * 64 + kq) ^ sw;
#pragma unroll
      for (int i = 0; i < 4; ++i) {
        short8 a = *(const short8*)(aC + (i * 16 + (l & 15)) * 512 + kb);
        acc[i] = __builtin_amdgcn_mfma_f32_16x16x32_bf16(a, bf8[s8], acc[i], 0, 0, 0);
      }
    }

    if (MODE == 1 || MODE == 2 || MODE == 4) {   // register stats accumulation
#pragma unroll
      for (int i = 0; i < 4; ++i) {
        const int r0 = tt * 64 + i * 16 + lrq;
#pragma unroll
        for (int q = 0; q < 4; ++q) {
          const float v = acc[i][q] + bj;
          if (r0 + q < E) { ssum += v; ssq = fmaf(v, v, ssq); }
        }
      }
    }
    if (MODE == 3 || MODE == 5) {                // act epilogue + row-dot into sRed
#pragma unroll
      for (int i = 0; i < 4; ++i) {
#pragma unroll
        for (int q = 0; q < 4; ++q) {
          const int lrow = i * 16 + lrq + q;
          float v = relu_(fmaf(acc[i][q], aE, cE));
          if (MODE == 3) {
            v += bfs(*(const short*)(aC + lrow * 512 + ((colfull * 2) ^ ((lrow & 7) << 4))));
            acc[i][q] = v;                       // out1 kept for pack
          }
          float p = v * wE;
          p += __shfl_xor(p, 1); p += __shfl_xor(p, 2);
          p += __shfl_xor(p, 4); p += __shfl_xor(p, 8);
          if ((l & 15) == 0) sRed[lrow * 8 + wv] = p;
        }
      }
    }
    __syncthreads();                             // aC reads done; aN visible; sRed visible

    if (MODE == 1 || MODE == 3) {
      const int odd = l & 1;                     // pack acc -> aC (bf16, own half cols)
#pragma unroll
      for (int i = 0; i < 4; ++i) {
        const int r0 = i * 16 + lrq;
        float v0 = acc[i][0], v1 = acc[i][1], v2 = acc[i][2], v3 = acc[i][3];
        float p0 = __shfl_xor(v0, 1), p1 = __shfl_xor(v1, 1);
        float p2 = __shfl_xor(v2, 1), p3 = __shfl_xor(v3, 1);
        float loA = odd ? p2 : v0, hiA = odd ? v2 : p0;
        float loB = odd ? p3 : v1, hiB = odd ? v3 : p1;
        const int ra = r0 + (odd ? 2 : 0);
        const int cp2 = (colfull & ~1) * 2;
        *(unsigned int*)(aC + (ra + 0) * 512 + (cp2 ^ (((ra + 0) & 7) << 4))) = packbf(loA, hiA);
        *(unsigned int*)(aC + (ra + 1) * 512 + (cp2 ^ (((ra + 1) & 7) << 4))) = packbf(loB, hiB);
      }
      if (MODE == 3 && t < 64) {                 // atomic partial-dot emit
        const int row = tt * 64 + t;
        if (row < E) {
          float s = 0.f;
#pragma unroll
          for (int w = 0; w < 8; ++w) s += sRed[t * 8 + w];
          atomicAdd(&out[row], s);
        }
      }
      __syncthreads();                           // pack visible
      {                                          // copy-out own 128-col half (16KB)
        char* d = (char*)buf + (size_t)tt * 32768 + half * 256;
#pragma unroll
        for (int r = 0; r < 2; ++r) {
          const int c = t + r * 512;             // 0..1023
          const int row = c >> 4;                // 0..63
          const int ch = c & 15;                 // 16B chunk in 256B half-row
          uint4 v = *(const uint4*)(aC + row * 512 + ((half * 256 + ch * 16) ^ ((row & 7) << 4)));
          *(uint4*)(d + row * 512 + ch * 16) = v;
        }
      }
      __syncthreads();                           // copy-out done (aC is next stage target)
    } else if (MODE == 5) {
      if (t < 64) {
        const int row = tt * 64 + t;
        if (row < E) {
          float s = 0.f;
#pragma unroll
          for (int w = 0; w < 8; ++w) s += sRed[t * 8 + w];
          atomicAdd(&out[row], s);
        }
      }
      __syncthreads();                           // sRed free for next iter
    }
    cur ^= 1;
  }

  if (MODE == 1 || MODE == 2 || MODE == 4) {     // stats: LDS reduce -> sliced atomics
    ssum += __shfl_xor(ssum, 16); ssum += __shfl_xor(ssum, 32);
    ssq  += __shfl_xor(ssq, 16);  ssq  += __shfl_xor(ssq, 32);
    if (l < 16) {
      sRed[wv * 16 + l] = ssum;                  // 128 col-sums (this half)
      sRed[128 + wv * 16 + l] = ssq;
    }
    __syncthreads();
    if (t < 128)      atomicAdd(&stats[xcd * 512 + half * 128 + t], sRed[t]);
    else if (t < 256) atomicAdd(&stats[xcd * 512 + 256 + half * 128 + (t - 128)], sRed[t]);
  }
#undef PREFETCH
#undef STAGE_A
}

extern "C" void kernel_launch(void* const* d_in, const int* in_sizes, int n_in,
                              void* d_out, int out_size, void* d_ws, size_t ws_size,
                              hipStream_t stream) {
  const float* x   = (const float*)d_in[0];
  const int*   ei  = (const int*)d_in[1];
  const float* W4  = (const float*)d_in[2];
  const float* b4  = (const float*)d_in[3];
  const float* g4  = (const float*)d_in[4];
  const float* be4 = (const float*)d_in[5];
  const float* W1  = (const float*)d_in[6];
  const float* b1  = (const float*)d_in[7];
  const float* g1  = (const float*)d_in[8];
  const float* be1 = (const float*)d_in[9];
  const float* W2  = (const float*)d_in[10];
  const float* b2  = (const float*)d_in[11];
  const float* g2  = (const float*)d_in[12];
  const float* be2 = (const float*)d_in[13];
  const float* Wf  = (const float*)d_in[14];
  const float* bfp = (const float*)d_in[15];
  float* out = (float*)d_out;

  const int E = out_size;
  const int MT = (E + 63) / 64;
  const int NBLK = 512;                     // 256 tile-ranges x 2 col-halves
  const float invE = 1.0f / (float)E;

  char* ws = (char*)d_ws;
  unsigned short* wt4 = (unsigned short*)(ws);
  unsigned short* wt1 = (unsigned short*)(ws + 131072);
  unsigned short* wt2 = (unsigned short*)(ws + 262144);
  float* stats = (float*)(ws + 393216);     // 3 layers x 8 slices x 512
  float* scale = (float*)(ws + 442368);     // 3 x (a, c_std, c_b)[256]
  int*   flag  = (int*)(ws + 451584);
  const size_t fixed = 458752;
  const size_t bufbytes = (size_t)MT * 32768;
  unsigned short* buf = (unsigned short*)(ws + fixed);

  if (ws_size < fixed + bufbytes) {
    k_bail<<<(E + 255) / 256, 256, 0, stream>>>(out, bfp, E);
    return;
  }

  k_init<<<1, 256, 0, stream>>>(ei, stats, flag);
  k_prep<<<192, 256, 0, stream>>>(W4, W1, W2, wt4, wt1, wt2);
  k_seed<<<(E + 255) / 256, 256, 0, stream>>>(out, bfp, E);

  // K1: gather -> G4 -> buf = Y4raw (half each), stats4
  kp<1><<<NBLK, 512, 0, stream>>>((const void*)x, ei, flag, wt4, b4,
                                  nullptr, nullptr, nullptr, buf, stats, nullptr, E, MT);
  k_stats<<<1, 256, 0, stream>>>(stats, g4, be4, b4, scale, invE);
  // K2: Y4raw --act4 on stage--> G1 -> stats1 (no store)
  kp<2><<<NBLK, 512, 0, stream>>>((const void*)buf, nullptr, flag, wt1, b1,
                                  scale, nullptr, nullptr, nullptr, stats + 4096, nullptr, E, MT);
  k_stats<<<1, 256, 0, stream>>>(stats + 4096, g1, be1, b1, scale + 768, invE);
  // K3: Y4raw --act4--> h; out1 = act1(G1)+h -> buf; out[e] += out1.wf
  kp<3><<<NBLK, 512, 0, stream>>>((const void*)buf, nullptr, flag, wt1, nullptr,
                                  scale, scale + 768, Wf, buf, nullptr, out, E, MT);
  // K4: out1 -> G2 -> stats2 (no store)
  kp<4><<<NBLK, 512, 0, stream>>>((const void*)buf, nullptr, flag, wt2, b2,
                                  nullptr, nullptr, nullptr, nullptr, stats + 8192, nullptr, E, MT);
  k_stats<<<1, 256, 0, stream>>>(stats + 8192, g2, be2, b2, scale + 1536, invE);
  // K5: out1 -> G2 -> out[e] += act2(acc).wf (no store)
  kp<5><<<NBLK, 512, 0, stream>>>((const void*)buf, nullptr, flag, wt2, nullptr,
                                  nullptr, scale + 1536, Wf, nullptr, nullptr, out, E, MT);
}

// Round 14
// 633.757 us; speedup vs baseline: 1.3939x; 1.3939x over previous
//
#include <hip/hip_runtime.h>
#include <hip/hip_bf16.h>
#include <stdint.h>

// GCNDecoder: round-6 proven structure (persistent 256 x 512thr, B fully LDS-resident
// 128KB + A tile 32KB = exactly 160KB, 8 waves, 1 block/CU, default reg heuristic -> 88
// VGPR no spill) + schedule trims from r9-r12:
//  K1: gather->G4 -> buf=Y4raw, stats4      K2: Y4raw --act4 on stage--> G1 -> stats1 (no store)
//  K3: Y4raw --act4--> h; out1=act1(G1)+h -> buf=out1; out[e] += out1.wf (seeded bf)
//  K4: out1 -> G2 -> stats2 (no store)      K5: out1 -> G2 -> out[e] += act2.wf (no store)
// vs r6: K4's 256MB store deleted; K5 scan replaced by GEMM-dot; 1 barrier/tile fewer.
// Residency lesson (r7-r13): 2 blocks/CU unreachable without <=64-reg waves (which spill);
// don't fight it — optimize within 1 block/CU.

typedef __attribute__((ext_vector_type(8))) short short8;
typedef __attribute__((ext_vector_type(4))) float f32x4;

__device__ __forceinline__ unsigned short bf16b(float f) {
  unsigned int u = __float_as_uint(f);
  return (unsigned short)((u + 0x7fffu + ((u >> 16) & 1u)) >> 16);  // RNE
}
__device__ __forceinline__ unsigned int packbf(float lo, float hi) {
  return (unsigned int)bf16b(lo) | ((unsigned int)bf16b(hi) << 16);
}
__device__ __forceinline__ float bflo(unsigned int u) { return __uint_as_float(u << 16); }
__device__ __forceinline__ float bfhi(unsigned int u) { return __uint_as_float(u & 0xffff0000u); }
__device__ __forceinline__ float bfs(short s) { return __uint_as_float(((unsigned int)(unsigned short)s) << 16); }
__device__ __forceinline__ float relu_(float x) { return fmaxf(x, 0.0f); }

// ---- tiny kernels ----
__global__ __launch_bounds__(256) void k_init(const int* __restrict__ ei,
                                              float* __restrict__ stats, int* __restrict__ flag) {
  const int t = threadIdx.x;
  for (int i = t; i < 1536; i += 256) stats[i] = 0.f;
  if (t == 0) {
    int o = 0;
#pragma unroll
    for (int i = 0; i < 32; ++i) o |= ei[2 * i + 1];
    *flag = (o == 0) ? 1 : 0;  // 1 => int64 pairs, 0 => int32
  }
}

__global__ __launch_bounds__(256) void k_seed(float* __restrict__ out, const float* __restrict__ bfp, int E) {
  const int i = blockIdx.x * 256 + threadIdx.x;
  if (i < E) out[i] = bfp[0];
}

__global__ __launch_bounds__(256) void k_bail(float* __restrict__ out, const float* __restrict__ bfp, int E) {
  const int i = blockIdx.x * 256 + threadIdx.x;
  if (i < E) out[i] = bfp[0];
}

// Wt[n][k] = bf16(W[k][n])  (n-major, 512B rows)
__global__ __launch_bounds__(256) void k_prep(
    const float* __restrict__ W4, const float* __restrict__ W1, const float* __restrict__ W2,
    unsigned short* __restrict__ wt4, unsigned short* __restrict__ wt1, unsigned short* __restrict__ wt2)
{
  const int b = blockIdx.x;
  const int t = threadIdx.x;
  const int wi = b >> 6;
  const int r = b & 63;
  const float* W = (wi == 0) ? W4 : (wi == 1) ? W1 : W2;
  unsigned short* Wt = (wi == 0) ? wt4 : (wi == 1) ? wt1 : wt2;
  const int flat = r * 1024 + t * 4;
  const int n = flat >> 8;
  const int k = flat & 255;
  ushort4 o;
  o.x = bf16b(W[(k + 0) * 256 + n]);
  o.y = bf16b(W[(k + 1) * 256 + n]);
  o.z = bf16b(W[(k + 2) * 256 + n]);
  o.w = bf16b(W[(k + 3) * 256 + n]);
  *(ushort4*)(Wt + flat) = o;
}

// stats -> scale[c]=a, scale[256+c]=c_std, scale[512+c]=c_b (bias folded)
__global__ __launch_bounds__(256) void k_stats(
    const float* __restrict__ stats, const float* __restrict__ g, const float* __restrict__ be,
    const float* __restrict__ bias, float* __restrict__ scale, float invE)
{
  const int c = threadIdx.x;
  const float mean = stats[c] * invE;
  const float var = stats[256 + c] * invE - mean * mean;
  const float a = g[c] * rsqrtf(var + 1e-5f);
  const float cstd = be[c] - mean * a;
  scale[c] = a;
  scale[256 + c] = cstd;
  scale[512 + c] = fmaf(a, bias[c], cstd);
}

// ---- persistent GEMM pass (512 thr, 8 waves 2x4; B resident in 128KB LDS) ----
// MODE 1: A=gather(x); store raw; stats        MODE 2: A=act4(buf); stats only
// MODE 3: A=act4(buf)=h; out1=act1(acc)+h; store out1; out[e] += out1.wf (atomic)
// MODE 4: A=buf raw; stats only                MODE 5: A=buf raw; out[e] += act2(acc).wf
template<int MODE>
__global__ __launch_bounds__(512, 1) void kp(
    const void* Asrc, const int* __restrict__ ei, const int* __restrict__ flagp,
    const unsigned short* __restrict__ Wt, const float* __restrict__ bias,
    const float* __restrict__ scst, const float* __restrict__ scep, const float* __restrict__ wf,
    unsigned short* __restrict__ buf, float* __restrict__ stats, float* __restrict__ out,
    int E, int MT)
{
  __shared__ __align__(16) char bB[131072];  // 256 n-rows x 512B (full K), XOR-swz by (n&7)<<4
  __shared__ __align__(16) char aT[32768];   // 64 rows x 512B, XOR-swz by (row&7)<<4

  const int t = threadIdx.x;
  const int b = blockIdx.x;
  const int per = MT >> 8, rem = MT & 255;
  const int t0 = b * per + (b < rem ? b : rem);
  const int t1 = t0 + per + (b < rem ? 1 : 0);

  const int l = t & 63, wv = t >> 6;
  const int wr = wv >> 2, wc = wv & 3;       // 2 x 4 wave grid
  const int sw = (l & 7) << 4;
  const int subc = t & 31, rB = t >> 5;      // staging: rows rB+r*16, byte-cols subc*16
  const int colb = wc * 64 + (l & 15);
  const int lr0 = wr * 32 + ((l >> 4) << 2);
  const int flag = (MODE == 1) ? flagp[0] : 0;

  float bj[4];                               // stats bias (MODE 1,2,4)
  if (MODE == 1 || MODE == 2 || MODE == 4) {
#pragma unroll
    for (int j = 0; j < 4; ++j) bj[j] = bias[colb + j * 16];
  }
  float aS[8], cS[8];                        // staging act4 scales (MODE 2,3)
  if (MODE == 2 || MODE == 3) {
#pragma unroll
    for (int k = 0; k < 8; ++k) { aS[k] = scst[subc * 8 + k]; cS[k] = scst[512 + subc * 8 + k]; }
  }
  float aE[4], cE[4], wE[4];                 // epilogue act scales + wf (MODE 3,5)
  if (MODE == 3 || MODE == 5) {
#pragma unroll
    for (int j = 0; j < 4; ++j) {
      const int c = colb + j * 16;
      aE[j] = scep[c]; cE[j] = scep[512 + c]; wE[j] = wf[c];
    }
  }
  float ssum[4] = {0.f, 0.f, 0.f, 0.f}, ssq[4] = {0.f, 0.f, 0.f, 0.f};

  uint4 pf[4];
#define PREFETCH(TT)                                                              \
  if (MODE == 1) {                                                                \
    const float* xf = (const float*)Asrc;                                         \
    _Pragma("unroll")                                                             \
    for (int r = 0; r < 4; ++r) {                                                 \
      const int row = rB + r * 16;                                                \
      int e = (TT) * 64 + row; if (e >= E) e = E - 1;                             \
      const int idx = (subc < 16) ? e : (E + e);                                  \
      const int node = flag ? ei[2 * idx] : ei[idx];                              \
      const float* s = xf + node * 128 + (subc & 15) * 8;                         \
      float4 f0 = *(const float4*)s;                                              \
      float4 f1 = *(const float4*)(s + 4);                                        \
      pf[r].x = packbf(f0.x, f0.y); pf[r].y = packbf(f0.z, f0.w);                 \
      pf[r].z = packbf(f1.x, f1.y); pf[r].w = packbf(f1.z, f1.w);                 \
    }                                                                             \
  } else {                                                                        \
    const uint4* s = (const uint4*)((const char*)Asrc + (size_t)(TT) * 32768);    \
    _Pragma("unroll")                                                             \
    for (int r = 0; r < 4; ++r) pf[r] = s[t + r * 512];                           \
  }

#define STAGE_A                                                                   \
  _Pragma("unroll")                                                               \
  for (int r = 0; r < 4; ++r) {                                                   \
    const int row = rB + r * 16;                                                  \
    uint4 v = pf[r];                                                              \
    if (MODE == 2 || MODE == 3) {                                                 \
      unsigned int* vp = (unsigned int*)&v;                                       \
      _Pragma("unroll")                                                           \
      for (int h2 = 0; h2 < 4; ++h2) {                                            \
        float lo = relu_(fmaf(bflo(vp[h2]), aS[h2 * 2], cS[h2 * 2]));             \
        float hi = relu_(fmaf(bfhi(vp[h2]), aS[h2 * 2 + 1], cS[h2 * 2 + 1]));     \
        vp[h2] = packbf(lo, hi);                                                  \
      }                                                                           \
    }                                                                             \
    *(uint4*)(aT + row * 512 + ((subc * 16) ^ ((row & 7) << 4))) = v;             \
  }

  PREFETCH(t0);
  // ---- stage B once (coalesced; 2-way LDS aliasing only) ----
#pragma unroll
  for (int r = 0; r < 16; ++r) {
    const int c = t + r * 512;
    uint4 v = *(const uint4*)(Wt + c * 8);
    const int n = c >> 5;
    *(uint4*)(bB + n * 512 + (((c & 31) * 16) ^ ((n & 7) << 4))) = v;
  }
  STAGE_A;
  if (t0 + 1 < t1) PREFETCH(t0 + 1);
  __syncthreads();

  const int ar = wr * 32 + (l & 15);
  const int bn = wc * 64 + (l & 15);

  for (int tt = t0; tt < t1; ++tt) {
    const bool more = (tt + 1 < t1);

    f32x4 acc[2][4];
    f32x4 zz = {0.f, 0.f, 0.f, 0.f};
#pragma unroll
    for (int i = 0; i < 2; ++i)
#pragma unroll
      for (int j = 0; j < 4; ++j) acc[i][j] = zz;

    // ---- barrier-free K loop: A and B both resident ----
#pragma unroll
    for (int ks = 0; ks < 4; ++ks) {
#pragma unroll
      for (int kk = 0; kk < 2; ++kk) {
        const int kb = ks * 128 + kk * 64 + ((l >> 4) << 4);
        short8 af[2], bfr[4];
        af[0] = *(const short8*)(aT + ar * 512 + (kb ^ sw));
        af[1] = *(const short8*)(aT + (ar + 16) * 512 + (kb ^ sw));
#pragma unroll
        for (int j = 0; j < 4; ++j)
          bfr[j] = *(const short8*)(bB + (bn + j * 16) * 512 + (kb ^ sw));
#pragma unroll
        for (int i = 0; i < 2; ++i)
#pragma unroll
          for (int j = 0; j < 4; ++j)
            acc[i][j] = __builtin_amdgcn_mfma_f32_16x16x32_bf16(af[i], bfr[j], acc[i][j], 0, 0, 0);
      }
    }

    if (MODE == 1 || MODE == 2 || MODE == 4) {   // register stats accumulation
#pragma unroll
      for (int i = 0; i < 2; ++i) {
        const int r0 = tt * 64 + lr0 + i * 16;
#pragma unroll
        for (int j = 0; j < 4; ++j) {
#pragma unroll
          for (int q = 0; q < 4; ++q) {
            const float v = acc[i][j][q] + bj[j];
            if (r0 + q < E) { ssum[j] += v; ssq[j] = fmaf(v, v, ssq[j]); }
          }
        }
      }
    } else {                                     // MODE 3/5: act epilogue + row-dot
      float dq[2][4];
#pragma unroll
      for (int i = 0; i < 2; ++i)
#pragma unroll
        for (int q = 0; q < 4; ++q) dq[i][q] = 0.f;
#pragma unroll
      for (int i = 0; i < 2; ++i) {
#pragma unroll
        for (int j = 0; j < 4; ++j) {
#pragma unroll
          for (int q = 0; q < 4; ++q) {
            const int lrow = lr0 + i * 16 + q;
            float v = relu_(fmaf(acc[i][j][q], aE[j], cE[j]));
            if (MODE == 3) {                     // + resid h from aT
              v += bfs(*(const short*)(aT + lrow * 512 +
                       (((colb + j * 16) * 2) ^ ((lrow & 7) << 4))));
              acc[i][j][q] = v;                  // out1 kept for pack
            }
            dq[i][q] = fmaf(v, wE[j], dq[i][q]);
          }
        }
      }
#pragma unroll
      for (int i = 0; i < 2; ++i)
#pragma unroll
        for (int q = 0; q < 4; ++q) {
          float p = dq[i][q];
          p += __shfl_xor(p, 1); p += __shfl_xor(p, 2);
          p += __shfl_xor(p, 4); p += __shfl_xor(p, 8);
          if ((l & 15) == 0) {
            const int row = tt * 64 + lr0 + i * 16 + q;
            if (row < E) atomicAdd(&out[row], p);
          }
        }
    }
    __syncthreads();                             // all aT reads done

    if (MODE == 1 || MODE == 3) {                // pack acc -> aT, then coalesced copy-out
      const int odd = l & 1;
#pragma unroll
      for (int i = 0; i < 2; ++i) {
        const int r0 = lr0 + i * 16;
#pragma unroll
        for (int j = 0; j < 4; ++j) {
          float v0 = acc[i][j][0], v1 = acc[i][j][1], v2 = acc[i][j][2], v3 = acc[i][j][3];
          float p0 = __shfl_xor(v0, 1), p1 = __shfl_xor(v1, 1);
          float p2 = __shfl_xor(v2, 1), p3 = __shfl_xor(v3, 1);
          float loA = odd ? p2 : v0, hiA = odd ? v2 : p0;
          float loB = odd ? p3 : v1, hiB = odd ? v3 : p1;
          const int ra = r0 + (odd ? 2 : 0);
          const int cp2 = ((colb + j * 16) & ~1) * 2;
          *(unsigned int*)(aT + (ra + 0) * 512 + (cp2 ^ (((ra + 0) & 7) << 4))) = packbf(loA, hiA);
          *(unsigned int*)(aT + (ra + 1) * 512 + (cp2 ^ (((ra + 1) & 7) << 4))) = packbf(loB, hiB);
        }
      }
      __syncthreads();                           // pack visible
      char* d = (char*)buf + (size_t)tt * 32768;
#pragma unroll
      for (int r = 0; r < 4; ++r) {
        const int c = t + r * 512;
        const int row = c >> 5;
        uint4 v = *(const uint4*)(aT + row * 512 + (((c & 31) * 16) ^ ((row & 7) << 4)));
        *(uint4*)(d + c * 16) = v;
      }
      __syncthreads();                           // copy-out reads done (aT is stage target)
    }

    if (more) {
      STAGE_A;                                   // A(tt+1) from prefetch regs
      if (tt + 2 < t1) PREFETCH(tt + 2);
      __syncthreads();                           // staged A visible for next K-loop
    }
  }

  if (MODE == 1 || MODE == 2 || MODE == 4) {     // stats tail: one atomic burst per block
#pragma unroll
    for (int j = 0; j < 4; ++j) {
      ssum[j] += __shfl_xor(ssum[j], 16); ssum[j] += __shfl_xor(ssum[j], 32);
      ssq[j]  += __shfl_xor(ssq[j], 16);  ssq[j]  += __shfl_xor(ssq[j], 32);
    }
    const int g = l >> 4;
    float sg = (g == 0) ? ssum[0] : (g == 1) ? ssum[1] : (g == 2) ? ssum[2] : ssum[3];
    float qg = (g == 0) ? ssq[0] : (g == 1) ? ssq[1] : (g == 2) ? ssq[2] : ssq[3];
    const int col = wc * 64 + g * 16 + (l & 15);
    atomicAdd(&stats[col], sg);
    atomicAdd(&stats[256 + col], qg);
  }
#undef PREFETCH
#undef STAGE_A
}

extern "C" void kernel_launch(void* const* d_in, const int* in_sizes, int n_in,
                              void* d_out, int out_size, void* d_ws, size_t ws_size,
                              hipStream_t stream) {
  const float* x   = (const float*)d_in[0];
  const int*   ei  = (const int*)d_in[1];
  const float* W4  = (const float*)d_in[2];
  const float* b4  = (const float*)d_in[3];
  const float* g4  = (const float*)d_in[4];
  const float* be4 = (const float*)d_in[5];
  const float* W1  = (const float*)d_in[6];
  const float* b1  = (const float*)d_in[7];
  const float* g1  = (const float*)d_in[8];
  const float* be1 = (const float*)d_in[9];
  const float* W2  = (const float*)d_in[10];
  const float* b2  = (const float*)d_in[11];
  const float* g2  = (const float*)d_in[12];
  const float* be2 = (const float*)d_in[13];
  const float* Wf  = (const float*)d_in[14];
  const float* bfp = (const float*)d_in[15];
  float* out = (float*)d_out;

  const int E = out_size;
  const int MT = (E + 63) / 64;
  const float invE = 1.0f / (float)E;

  char* ws = (char*)d_ws;
  unsigned short* wt4 = (unsigned short*)(ws);
  unsigned short* wt1 = (unsigned short*)(ws + 131072);
  unsigned short* wt2 = (unsigned short*)(ws + 262144);
  float* stats = (float*)(ws + 393216);     // 3 x 512
  float* scale = (float*)(ws + 399360);     // 3 x (a, c_std, c_b)[256]
  int*   flag  = (int*)(ws + 408576);
  const size_t fixed = 409600;
  const size_t bufbytes = (size_t)MT * 32768;
  unsigned short* buf = (unsigned short*)(ws + fixed);

  if (ws_size < fixed + bufbytes) {
    k_bail<<<(E + 255) / 256, 256, 0, stream>>>(out, bfp, E);
    return;
  }

  k_init<<<1, 256, 0, stream>>>(ei, stats, flag);
  k_prep<<<192, 256, 0, stream>>>(W4, W1, W2, wt4, wt1, wt2);

  // K1: gather -> G4 -> buf = Y4raw, stats4
  kp<1><<<256, 512, 0, stream>>>((const void*)x, ei, flag, wt4, b4,
                                 nullptr, nullptr, nullptr, buf, stats, nullptr, E, MT);
  k_stats<<<1, 256, 0, stream>>>(stats, g4, be4, b4, scale, invE);
  // K2: Y4raw --act4 on stage--> G1 -> stats1 (no store)
  kp<2><<<256, 512, 0, stream>>>((const void*)buf, nullptr, flag, wt1, b1,
                                 scale, nullptr, nullptr, nullptr, stats + 512, nullptr, E, MT);
  k_stats<<<1, 256, 0, stream>>>(stats + 512, g1, be1, b1, scale + 768, invE);
  k_seed<<<(E + 255) / 256, 256, 0, stream>>>(out, bfp, E);
  // K3: Y4raw --act4--> h; out1 = act1(G1)+h -> buf = out1; out[e] += out1.wf
  kp<3><<<256, 512, 0, stream>>>((const void*)buf, nullptr, flag, wt1, nullptr,
                                 scale, scale + 768, Wf, buf, nullptr, out, E, MT);
  // K4: out1 -> G2 -> stats2 (no store)
  kp<4><<<256, 512, 0, stream>>>((const void*)buf, nullptr, flag, wt2, b2,
                                 nullptr, nullptr, nullptr, nullptr, stats + 1024, nullptr, E, MT);
  k_stats<<<1, 256, 0, stream>>>(stats + 1024, g2, be2, b2, scale + 1536, invE);
  // K5: out1 -> G2 -> out[e] += act2(acc).wf (no store)
  kp<5><<<256, 512, 0, stream>>>((const void*)buf, nullptr, flag, wt2, nullptr,
                                 nullptr, scale + 1536, Wf, nullptr, nullptr, out, E, MT);
}